// Round 8
// baseline (151.987 us; speedup 1.0000x reference)
//
#include <hip/hip_runtime.h>
#include <hip/hip_bf16.h>
#include <cstddef>
#include <cstdint>

// JastrowNet fully fused: ONE kernel, one block (1024 thr = 16 waves) per batch.
// Filter MLP (32->16->8, ssp) per 16-row tile:
//   MFMA-1: mfma_f32_16x16x32_bf16  D1 = W1^T x rows^T + b1
//           lane (g4,r16) holds h1[hidden=g4*4+r][row=r16]
//   MFMA-2: mfma_f32_16x16x16_bf16  (K=16 = hidden) -- B-fragment layout is
//           IDENTICAL to D1's D-fragment: ssp(d1) -> 4 in-lane cvt -> B2.
// Wave schedule (wid 0..15): even wid -> same-spin, odd -> anti, 4 tiles each;
// all waves 1 nuclear tile.
// R7 post-mortem: ~50 us invariant across structures; VALU-issue-bound
// (VALUBusy 55%, HBM 10%, Mfma 2%). Biggest redundant chunk: per-wave weight
// fragment builds (scattered loads + ~70 f2bf per wave, x16 waves, identical
// data). R8: stage ALL weight fragments ONCE per block into LDS, pre-converted
// bf16 in transposed fragment layout -> per-wave fragment fetch is 1
// ds_read_b128 (A1) + 1 ds_read_b64 (A2) + 2 aligned float4 bias reads per
// layer. Edge/nuc tile-0 loads hoisted above the staging barrier. Arithmetic
// bit-identical to R7.  Workspace unused.

#define NB   512
#define NE   32
#define NA   8
#define NF   32
#define NH   16
#define NK   8
#define NEMB 16

typedef __attribute__((ext_vector_type(8))) short short8;
typedef __attribute__((ext_vector_type(4))) short short4b;
typedef __attribute__((ext_vector_type(4))) float f32x4;

#define LN2 0.69314718055994530942f

// ssp(v) = softplus(v) - ln2; inputs bounded -> direct form safe.
__device__ __forceinline__ float ssp(float v){
    return __logf(1.f + __expf(v)) - LN2;
}

// fp32 -> bf16 bits, round-to-nearest-even (finite inputs) -- proven path
__device__ __forceinline__ short f2bf(float x){
    unsigned b = __float_as_uint(x);
    b += 0x7fffu + ((b >> 16) & 1u);
    return (short)(b >> 16);
}
__device__ __forceinline__ unsigned packbf2(float lo, float hi){
    return (unsigned)(unsigned short)f2bf(lo) | ((unsigned)(unsigned short)f2bf(hi) << 16);
}
__device__ __forceinline__ short8 cvt_row(float4 a, float4 b){
    short8 s;
    s[0]=f2bf(a.x); s[1]=f2bf(a.y); s[2]=f2bf(a.z); s[3]=f2bf(a.w);
    s[4]=f2bf(b.x); s[5]=f2bf(b.y); s[6]=f2bf(b.z); s[7]=f2bf(b.w);
    return s;
}

__device__ __forceinline__ f32x4 mfma16x16(short4b a, short4b b, f32x4 c){
#if __has_builtin(__builtin_amdgcn_mfma_f32_16x16x16bf16_1k)
    return __builtin_amdgcn_mfma_f32_16x16x16bf16_1k(a, b, c, 0, 0, 0);
#else
    f32x4 d;
    asm("s_nop 1\n\tv_mfma_f32_16x16x16_bf16 %0, %1, %2, %3\n\ts_nop 7"
        : "=v"(d) : "v"(a), "v"(b), "v"(c));
    return d;
#endif
}

extern "C" __global__ void __launch_bounds__(1024, 4)
jastrow_kernel(const float* __restrict__ edges_elec,
               const float* __restrict__ edges_nuc,
               const float* __restrict__ X_emb,
               const float* __restrict__ Yk,
               const float* __restrict__ wW1, const float* __restrict__ wb1,
               const float* __restrict__ wW2, const float* __restrict__ wb2,
               const float* __restrict__ hW,  const float* __restrict__ hb,
               const float* __restrict__ gW,  const float* __restrict__ gb,
               const float* __restrict__ orbW,
               float* __restrict__ out)
{
    __shared__ __align__(16) __hip_bfloat16 s_w2[NE*NE*NK];  // 16384 B
    __shared__ __align__(16) float s_z1p[2*NE*NK];           //  2048 B
    __shared__ __align__(16) float s_zn1[NE*NK];             //  1024 B
    __shared__ __align__(16) float s_zn2[NE*NK];             //  1024 B
    __shared__ float s_hx1[2*NK];
    __shared__ float s_x[NE*NEMB];                           //  2048 B
    __shared__ float s_z[NE*NK];                             //  1024 B
    __shared__ float s_hx[NE*NK];                            //  1024 B
    __shared__ float s_red[16];
    // pre-converted weight fragments (transposed layouts)
    __shared__ __align__(16) short s_w1T[3][2][NH][NF];      //  6144 B [cc][l][h][f]
    __shared__ __align__(16) short s_w2T[3][2][16][NH];      //  3072 B [cc][l][k(16,8 zero)][h]
    __shared__ __align__(16) float s_b1[3][2][NH];           //   384 B
    __shared__ __align__(16) float s_b2[3][2][16];           //   384 B (rows 8-15 zero)

    const int b = blockIdx.x, t = threadIdx.x;
    const int wid = t >> 6, lane = t & 63;
    const int r16 = lane & 15, g4 = lane >> 4;

    // ---- hoist this wave's edge loads (independent of LDS staging) ----
    const int ccE = wid & 1;
    const int wq  = (wid >> 1) * 4;
    auto esrc = [&](int u) -> const float* {
        const int tau = wq + u;
        const int qi = tau >> 4, g = tau & 15;
        const int qj = ccE ? (1 - qi) : qi;
        return edges_elec + (((size_t)b*NE + qi*16 + g)*NE + qj*16 + r16)*NF + g4*8;
    };
    float4 ra = ((const float4*)esrc(0))[0];
    float4 rb = ((const float4*)esrc(0))[1];
    const int nm = lane & 7;
    const int ni = 2*wid + (r16 >> 3);
    const float* nsrc = edges_nuc + (((size_t)b*NE + ni)*NA + nm)*NF + g4*8;
    const float4 nra = ((const float4*)nsrc)[0];
    const float4 nrb = ((const float4*)nsrc)[1];

    // ---- stage weight fragments (once per block, pre-converted bf16) ----
    // w1T[cc][l][h][f] = bf16(wW1[l,cc][f][h])
    for (int idx = t; idx < 3*2*NH*NF; idx += 1024){
        const int f = idx & 31, h = (idx >> 5) & 15;
        const int l = (idx >> 9) & 1, cc = idx >> 10;
        s_w1T[cc][l][h][f] = f2bf(wW1[((size_t)(l*3 + cc)*NF + f)*NH + h]);
    }
    // w2T[cc][l][k][h] = k<8 ? bf16(wW2[l,cc][h][k]) : 0
    for (int idx = t; idx < 3*2*16*NH; idx += 1024){
        const int h = idx & 15, k = (idx >> 4) & 15;
        const int l = (idx >> 8) & 1, cc = idx >> 9;
        s_w2T[cc][l][k][h] = (k < NK)
            ? f2bf(wW2[((size_t)(l*3 + cc)*NH + h)*NK + k]) : (short)0;
    }
    if (t < 3*2*NH){
        const int m = t & 15, l = (t >> 4) & 1, cc = t >> 5;
        s_b1[cc][l][m] = wb1[(l*3 + cc)*NH + m];
        s_b2[cc][l][m] = (m < NK) ? wb2[(l*3 + cc)*NK + m] : 0.f;
    }
    // hx1[s][k] = ssp(X_emb[s] @ hW[0] + hb[0]) (spin-only)
    if (t >= 1008){  // 16 threads of the last wave (doesn't collide with above)
        const int tt = t - 1008;
        const int s = tt >> 3, k = tt & 7;
        float acc = hb[k];
#pragma unroll
        for (int e = 0; e < NEMB; e++)
            acc = fmaf(X_emb[s*NEMB + e], hW[e*NK + k], acc);
        s_hx1[tt] = ssp(acc);
    }
    __syncthreads();

    // ---- per-wave fragment fetch: electron channel ----
    short8 a1[2]; short4b a2[2]; f32x4 c1[2], c2[2];
#pragma unroll
    for (int l = 0; l < 2; l++){
        a1[l] = *(const short8*)&s_w1T[ccE][l][r16][g4*8];
        a2[l] = *(const short4b*)&s_w2T[ccE][l][r16][g4*4];
        c1[l] = *(const f32x4*)&s_b1[ccE][l][g4*4];
        c2[l] = *(const f32x4*)&s_b2[ccE][l][g4*4];
    }

#pragma unroll
    for (int u = 0; u < 4; u++){
        float4 nxa = ra, nxb = rb;           // defined at u==3 (self; dead after)
        if (u < 3){
            const float* src = esrc(u + 1);
            nxa = ((const float4*)src)[0];
            nxb = ((const float4*)src)[1];
        }
        const int tau = wq + u;
        const int qi = tau >> 4, g = tau & 15;
        const int qj = ccE ? (1 - qi) : qi;
        const int i  = qi*16 + g;
        const short8 bfr = cvt_row(ra, rb);
#pragma unroll
        for (int l = 0; l < 2; l++){
            f32x4 d1 = __builtin_amdgcn_mfma_f32_16x16x32_bf16(a1[l], bfr, c1[l], 0, 0, 0);
            short4b bb;
            bb[0] = f2bf(ssp(d1[0]));
            bb[1] = f2bf(ssp(d1[1]));
            bb[2] = f2bf(ssp(d1[2]));
            bb[3] = f2bf(ssp(d1[3]));
            f32x4 d2 = mfma16x16(a2[l], bb, c2[l]);
            float wk[4];
#pragma unroll
            for (int r = 0; r < 4; r++) wk[r] = ssp(d2[r]);
            if (ccE == 0 && r16 == g){
#pragma unroll
                for (int r = 0; r < 4; r++) wk[r] = 0.f;
            }
            if (l == 0){
                // z1 partial: sum over j (=r16), scale by hx1[spin(j)=qj]
#pragma unroll
                for (int off = 1; off < 16; off <<= 1)
#pragma unroll
                    for (int r = 0; r < 4; r++) wk[r] += __shfl_xor(wk[r], off, 64);
                if (r16 == 0 && g4 < 2){
                    float4 st;
                    st.x = wk[0]*s_hx1[qj*NK + g4*4 + 0];
                    st.y = wk[1]*s_hx1[qj*NK + g4*4 + 1];
                    st.z = wk[2]*s_hx1[qj*NK + g4*4 + 2];
                    st.w = wk[3]*s_hx1[qj*NK + g4*4 + 3];
                    *(float4*)&s_z1p[(qj*NE + i)*NK + g4*4] = st;
                }
            } else if (g4 < 2){
                const int j = qj*16 + r16;
                uint2 uu;
                uu.x = packbf2(wk[0], wk[1]);
                uu.y = packbf2(wk[2], wk[3]);
                *(uint2*)&s_w2[(i*NE + j)*NK + g4*4] = uu;
            }
        }
        ra = nxa; rb = nxb;
    }

    // ---- nuclear channel (all 16 waves, one tile each; loads hoisted) ----
    {
#pragma unroll
        for (int l = 0; l < 2; l++){
            a1[l] = *(const short8*)&s_w1T[2][l][r16][g4*8];
            a2[l] = *(const short4b*)&s_w2T[2][l][r16][g4*4];
            c1[l] = *(const f32x4*)&s_b1[2][l][g4*4];
            c2[l] = *(const f32x4*)&s_b2[2][l][g4*4];
        }
        float Yv[4];
#pragma unroll
        for (int r = 0; r < 4; r++)
            Yv[r] = Yk[nm*NK + ((g4*4 + r) & 7)];
        const short8 bfr = cvt_row(nra, nrb);
#pragma unroll
        for (int l = 0; l < 2; l++){
            f32x4 d1 = __builtin_amdgcn_mfma_f32_16x16x32_bf16(a1[l], bfr, c1[l], 0, 0, 0);
            short4b bb;
            bb[0] = f2bf(ssp(d1[0]));
            bb[1] = f2bf(ssp(d1[1]));
            bb[2] = f2bf(ssp(d1[2]));
            bb[3] = f2bf(ssp(d1[3]));
            f32x4 d2 = mfma16x16(a2[l], bb, c2[l]);
            float wk[4];
#pragma unroll
            for (int r = 0; r < 4; r++) wk[r] = ssp(d2[r]) * Yv[r];
#pragma unroll
            for (int off = 1; off < 8; off <<= 1)
#pragma unroll
                for (int r = 0; r < 4; r++) wk[r] += __shfl_xor(wk[r], off, 64);
            if ((r16 & 7) == 0 && g4 < 2){
                float* dst = l ? s_zn2 : s_zn1;
                float4 st; st.x = wk[0]; st.y = wk[1]; st.z = wk[2]; st.w = wk[3];
                *(float4*)&dst[ni*NK + g4*4] = st;
            }
        }
    }
    __syncthreads();

    // ================= per-batch sequential update =================
    // x1 = x0 + z1 @ gW0 + gb0   (z1 folded inline: z1p halves + zn1)
    if (t < NE*NEMB){
        const int i = t >> 4, e = t & 15;
        float acc = gb[e];
#pragma unroll
        for (int k = 0; k < NK; k++){
            const float zk = s_z1p[i*NK + k] + s_z1p[NE*NK + i*NK + k]
                           + s_zn1[i*NK + k];
            acc = fmaf(zk, gW[k*NEMB + e], acc);
        }
        s_x[t] = X_emb[(i >> 4)*NEMB + e] + acc;
    }
    __syncthreads();
    // hx2 = ssp(x1 @ hW1 + hb1)
    if (t < NE*NK){
        const int i = t >> 3, k = t & 7;
        float acc = hb[NK + k];
#pragma unroll
        for (int e = 0; e < NEMB; e++)
            acc = fmaf(s_x[i*NEMB + e], hW[NEMB*NK + e*NK + k], acc);
        s_hx[t] = ssp(acc);
    }
    __syncthreads();
    // z2[i,k] = sum_j w2[i,j,k]*hx2[j,k]  (+ zn2)
    if (t < NE*NEMB){
        const int i = t >> 4, j16 = t & 15;
        float zacc[NK];
#pragma unroll
        for (int k = 0; k < NK; k++) zacc[k] = 0.f;
#pragma unroll
        for (int qj = 0; qj < 2; qj++){
            const int j = qj*16 + j16;
            union { uint4 u; __hip_bfloat16 h[8]; } raw;
            raw.u = *(const uint4*)&s_w2[((size_t)i*NE + j)*NK];
            float pk[NK];
#pragma unroll
            for (int k = 0; k < NK; k++)
                pk[k] = __bfloat162float(raw.h[k]) * s_hx[j*NK + k];
#pragma unroll
            for (int off = 8; off > 0; off >>= 1)
#pragma unroll
                for (int k = 0; k < NK; k++) pk[k] += __shfl_down(pk[k], off, 16);
#pragma unroll
            for (int k = 0; k < NK; k++) zacc[k] += pk[k];
        }
        if (j16 == 0){
#pragma unroll
            for (int k = 0; k < NK; k++)
                s_z[i*NK + k] = zacc[k] + s_zn2[i*NK + k];
        }
    }
    __syncthreads();
    // x2 = x1 + z2 @ gW1 + gb1
    if (t < NE*NEMB){
        const int i = t >> 4, e = t & 15;
        float acc = gb[NEMB + e];
#pragma unroll
        for (int k = 0; k < NK; k++)
            acc = fmaf(s_z[i*NK + k], gW[NK*NEMB + k*NEMB + e], acc);
        s_x[t] += acc;
    }
    __syncthreads();
    // readout: sum_i x2[i] @ orbW
    float part = (t < NE*NEMB) ? s_x[t] * orbW[t & 15] : 0.f;
#pragma unroll
    for (int off = 32; off > 0; off >>= 1) part += __shfl_down(part, off, 64);
    if (lane == 0) s_red[wid] = part;
    __syncthreads();
    if (t == 0){
        float r = 0.f;
#pragma unroll
        for (int w = 0; w < 16; w++) r += s_red[w];
        out[b] = r;
    }
}

extern "C" void kernel_launch(void* const* d_in, const int* in_sizes, int n_in,
                              void* d_out, int out_size, void* d_ws, size_t ws_size,
                              hipStream_t stream)
{
    const float* edges_elec = (const float*)d_in[0];
    const float* edges_nuc  = (const float*)d_in[1];
    const float* X_emb      = (const float*)d_in[2];
    const float* Yk         = (const float*)d_in[3];
    const float* wW1        = (const float*)d_in[4];
    const float* wb1        = (const float*)d_in[5];
    const float* wW2        = (const float*)d_in[6];
    const float* wb2        = (const float*)d_in[7];
    const float* hW         = (const float*)d_in[8];
    const float* hb         = (const float*)d_in[9];
    const float* gW         = (const float*)d_in[10];
    const float* gb         = (const float*)d_in[11];
    const float* orbW       = (const float*)d_in[12];

    jastrow_kernel<<<NB, 1024, 0, stream>>>(
        edges_elec, edges_nuc, X_emb, Yk, wW1, wb1, wW2, wb2, hW, hb,
        gW, gb, orbW, (float*)d_out);
}

// Round 9
// 147.534 us; speedup vs baseline: 1.0302x; 1.0302x over previous
//
#include <hip/hip_runtime.h>
#include <hip/hip_bf16.h>
#include <cstddef>
#include <cstdint>

// JastrowNet fully fused: ONE kernel, one block (1024 thr = 16 waves) per batch.
// Filter MLP (32->16->8, ssp) per 16-row tile:
//   MFMA-1: mfma_f32_16x16x32_bf16  D1 = W1^T x rows^T + b1
//   MFMA-2: mfma_f32_16x16x16_bf16  (K=16) -- B2 frag == D1 frag, no shuffles.
// R8 post-mortem: ~50us invariant across VALU count / occupancy / spills since
// R1. The never-ablated constant: serial cross-lane __shfl reduction chains
// (z1: 4-deep x16 ds_swizzle per tile; nuc: 3-deep x2) + divergent l0/l1 paths.
// R9: ZERO cross-lane ops in the filter phase. Both layers store masked bf16
// filters to LDS (w1 16KB new, w2 16KB, wn 9KB unscaled); ALL contractions
// (z1, zn1/2, z2) become per-(i,k)-thread LDS loops in the update phase
// (no shuffles there either). Padded i-strides avoid bank conflicts.
// Wave schedule unchanged: even wid -> same-spin, odd -> anti, 4 tiles each;
// all waves 1 nuclear tile.  Workspace unused.

#define NB   512
#define NE   32
#define NA   8
#define NF   32
#define NH   16
#define NK   8
#define NEMB 16

#define W_STRIDE  264   // shorts per i-row of s_w1/s_w2 (32*8 + 8 pad)
#define WN_STRIDE 72    // shorts per i-row of s_wn    ( 8*8 + 8 pad)

typedef __attribute__((ext_vector_type(8))) short short8;
typedef __attribute__((ext_vector_type(4))) short short4b;
typedef __attribute__((ext_vector_type(4))) float f32x4;

#define LN2 0.69314718055994530942f

// ssp(v) = softplus(v) - ln2; inputs bounded -> direct form safe.
__device__ __forceinline__ float ssp(float v){
    return __logf(1.f + __expf(v)) - LN2;
}

// fp32 -> bf16 bits, round-to-nearest-even (finite inputs) -- proven path
__device__ __forceinline__ short f2bf(float x){
    unsigned b = __float_as_uint(x);
    b += 0x7fffu + ((b >> 16) & 1u);
    return (short)(b >> 16);
}
__device__ __forceinline__ unsigned packbf2(float lo, float hi){
    return (unsigned)(unsigned short)f2bf(lo) | ((unsigned)(unsigned short)f2bf(hi) << 16);
}
__device__ __forceinline__ float bf2f(short s){
    return __uint_as_float(((unsigned)(unsigned short)s) << 16);
}
__device__ __forceinline__ short8 cvt_row(float4 a, float4 b){
    short8 s;
    s[0]=f2bf(a.x); s[1]=f2bf(a.y); s[2]=f2bf(a.z); s[3]=f2bf(a.w);
    s[4]=f2bf(b.x); s[5]=f2bf(b.y); s[6]=f2bf(b.z); s[7]=f2bf(b.w);
    return s;
}

__device__ __forceinline__ f32x4 mfma16x16(short4b a, short4b b, f32x4 c){
#if __has_builtin(__builtin_amdgcn_mfma_f32_16x16x16bf16_1k)
    return __builtin_amdgcn_mfma_f32_16x16x16bf16_1k(a, b, c, 0, 0, 0);
#else
    f32x4 d;
    asm("s_nop 1\n\tv_mfma_f32_16x16x16_bf16 %0, %1, %2, %3\n\ts_nop 7"
        : "=v"(d) : "v"(a), "v"(b), "v"(c));
    return d;
#endif
}

extern "C" __global__ void __launch_bounds__(1024, 4)
jastrow_kernel(const float* __restrict__ edges_elec,
               const float* __restrict__ edges_nuc,
               const float* __restrict__ X_emb,
               const float* __restrict__ Yk,
               const float* __restrict__ wW1, const float* __restrict__ wb1,
               const float* __restrict__ wW2, const float* __restrict__ wb2,
               const float* __restrict__ hW,  const float* __restrict__ hb,
               const float* __restrict__ gW,  const float* __restrict__ gb,
               const float* __restrict__ orbW,
               float* __restrict__ out)
{
    __shared__ __align__(16) short s_w1[NE*W_STRIDE];        // 16896 B
    __shared__ __align__(16) short s_w2[NE*W_STRIDE];        // 16896 B
    __shared__ __align__(16) short s_wn[2][NE*WN_STRIDE];    //  9216 B
    __shared__ float s_hx1[2*NK];
    __shared__ float s_Y[NA*NK];                             //   256 B
    __shared__ float s_x[NE*NEMB];                           //  2048 B
    __shared__ float s_z[NE*NK];                             //  1024 B
    __shared__ float s_hx[NE*NK];                            //  1024 B
    __shared__ float s_red[16];
    // pre-converted weight fragments (transposed layouts)
    __shared__ __align__(16) short s_w1T[3][2][NH][NF];      //  6144 B
    __shared__ __align__(16) short s_w2T[3][2][16][NH];      //  3072 B
    __shared__ __align__(16) float s_b1[3][2][NH];
    __shared__ __align__(16) float s_b2[3][2][16];

    const int b = blockIdx.x, t = threadIdx.x;
    const int wid = t >> 6, lane = t & 63;
    const int r16 = lane & 15, g4 = lane >> 4;

    // ---- hoist this wave's edge loads (independent of LDS staging) ----
    const int ccE = wid & 1;
    const int wq  = (wid >> 1) * 4;
    auto esrc = [&](int u) -> const float* {
        const int tau = wq + u;
        const int qi = tau >> 4, g = tau & 15;
        const int qj = ccE ? (1 - qi) : qi;
        return edges_elec + (((size_t)b*NE + qi*16 + g)*NE + qj*16 + r16)*NF + g4*8;
    };
    float4 ra = ((const float4*)esrc(0))[0];
    float4 rb = ((const float4*)esrc(0))[1];
    const int nm = lane & 7;
    const int ni = 2*wid + (r16 >> 3);
    const float* nsrc = edges_nuc + (((size_t)b*NE + ni)*NA + nm)*NF + g4*8;
    const float4 nra = ((const float4*)nsrc)[0];
    const float4 nrb = ((const float4*)nsrc)[1];

    // ---- stage weight fragments (once per block, pre-converted bf16) ----
    for (int idx = t; idx < 3*2*NH*NF; idx += 1024){
        const int f = idx & 31, h = (idx >> 5) & 15;
        const int l = (idx >> 9) & 1, cc = idx >> 10;
        s_w1T[cc][l][h][f] = f2bf(wW1[((size_t)(l*3 + cc)*NF + f)*NH + h]);
    }
    for (int idx = t; idx < 3*2*16*NH; idx += 1024){
        const int h = idx & 15, k = (idx >> 4) & 15;
        const int l = (idx >> 8) & 1, cc = idx >> 9;
        s_w2T[cc][l][k][h] = (k < NK)
            ? f2bf(wW2[((size_t)(l*3 + cc)*NH + h)*NK + k]) : (short)0;
    }
    if (t < 3*2*NH){
        const int m = t & 15, l = (t >> 4) & 1, cc = t >> 5;
        s_b1[cc][l][m] = wb1[(l*3 + cc)*NH + m];
        s_b2[cc][l][m] = (m < NK) ? wb2[(l*3 + cc)*NK + m] : 0.f;
    }
    if (t >= 896 && t < 896 + NA*NK)
        s_Y[t - 896] = Yk[t - 896];
    // hx1[s][k] = ssp(X_emb[s] @ hW[0] + hb[0]) (spin-only)
    if (t >= 1008){
        const int tt = t - 1008;
        const int s = tt >> 3, k = tt & 7;
        float acc = hb[k];
#pragma unroll
        for (int e = 0; e < NEMB; e++)
            acc = fmaf(X_emb[s*NEMB + e], hW[e*NK + k], acc);
        s_hx1[tt] = ssp(acc);
    }
    __syncthreads();

    // ---- per-wave fragment fetch: electron channel ----
    short8 a1[2]; short4b a2[2]; f32x4 c1[2], c2[2];
#pragma unroll
    for (int l = 0; l < 2; l++){
        a1[l] = *(const short8*)&s_w1T[ccE][l][r16][g4*8];
        a2[l] = *(const short4b*)&s_w2T[ccE][l][r16][g4*4];
        c1[l] = *(const f32x4*)&s_b1[ccE][l][g4*4];
        c2[l] = *(const f32x4*)&s_b2[ccE][l][g4*4];
    }

#pragma unroll
    for (int u = 0; u < 4; u++){
        float4 nxa = ra, nxb = rb;           // defined at u==3 (self; dead after)
        if (u < 3){
            const float* src = esrc(u + 1);
            nxa = ((const float4*)src)[0];
            nxb = ((const float4*)src)[1];
        }
        const int tau = wq + u;
        const int qi = tau >> 4, g = tau & 15;
        const int qj = ccE ? (1 - qi) : qi;
        const int i  = qi*16 + g;
        const int j  = qj*16 + r16;
        const short8 bfr = cvt_row(ra, rb);
#pragma unroll
        for (int l = 0; l < 2; l++){
            f32x4 d1 = __builtin_amdgcn_mfma_f32_16x16x32_bf16(a1[l], bfr, c1[l], 0, 0, 0);
            short4b bb;
            bb[0] = f2bf(ssp(d1[0]));
            bb[1] = f2bf(ssp(d1[1]));
            bb[2] = f2bf(ssp(d1[2]));
            bb[3] = f2bf(ssp(d1[3]));
            f32x4 d2 = mfma16x16(a2[l], bb, c2[l]);
            float wk[4];
#pragma unroll
            for (int r = 0; r < 4; r++) wk[r] = ssp(d2[r]);
            if (ccE == 0 && r16 == g){
#pragma unroll
                for (int r = 0; r < 4; r++) wk[r] = 0.f;
            }
            if (g4 < 2){
                short* dst = l ? s_w2 : s_w1;
                uint2 uu;
                uu.x = packbf2(wk[0], wk[1]);
                uu.y = packbf2(wk[2], wk[3]);
                *(uint2*)&dst[i*W_STRIDE + j*NK + g4*4] = uu;
            }
        }
        ra = nxa; rb = nxb;
    }

    // ---- nuclear channel (all 16 waves, one tile each; loads hoisted) ----
    {
#pragma unroll
        for (int l = 0; l < 2; l++){
            a1[l] = *(const short8*)&s_w1T[2][l][r16][g4*8];
            a2[l] = *(const short4b*)&s_w2T[2][l][r16][g4*4];
            c1[l] = *(const f32x4*)&s_b1[2][l][g4*4];
            c2[l] = *(const f32x4*)&s_b2[2][l][g4*4];
        }
        const short8 bfr = cvt_row(nra, nrb);
#pragma unroll
        for (int l = 0; l < 2; l++){
            f32x4 d1 = __builtin_amdgcn_mfma_f32_16x16x32_bf16(a1[l], bfr, c1[l], 0, 0, 0);
            short4b bb;
            bb[0] = f2bf(ssp(d1[0]));
            bb[1] = f2bf(ssp(d1[1]));
            bb[2] = f2bf(ssp(d1[2]));
            bb[3] = f2bf(ssp(d1[3]));
            f32x4 d2 = mfma16x16(a2[l], bb, c2[l]);
            if (g4 < 2){
                uint2 uu;
                uu.x = packbf2(ssp(d2[0]), ssp(d2[1]));
                uu.y = packbf2(ssp(d2[2]), ssp(d2[3]));
                *(uint2*)&s_wn[l][ni*WN_STRIDE + nm*NK + g4*4] = uu;
            }
        }
    }
    __syncthreads();

    // ================= per-batch sequential update =================
    // z1[i,k] = sum_j w1[i,j,k]*hx1[spin(j),k] + sum_m wn1[i,m,k]*Y[m,k]
    if (t < NE*NK){
        const int i = t >> 3, k = t & 7;
        float p0 = 0.f, p1 = 0.f;
#pragma unroll
        for (int j = 0; j < 16; j++){
            p0 += bf2f(s_w1[i*W_STRIDE + j*NK + k]);
            p1 += bf2f(s_w1[i*W_STRIDE + (16 + j)*NK + k]);
        }
        float z1 = p0*s_hx1[k] + p1*s_hx1[NK + k];
#pragma unroll
        for (int m = 0; m < NA; m++)
            z1 = fmaf(bf2f(s_wn[0][i*WN_STRIDE + m*NK + k]), s_Y[m*NK + k], z1);
        s_z[t] = z1;
    }
    __syncthreads();
    // x1 = x0 + z1 @ gW0 + gb0
    if (t < NE*NEMB){
        const int i = t >> 4, e = t & 15;
        float acc = gb[e];
#pragma unroll
        for (int k = 0; k < NK; k++)
            acc = fmaf(s_z[i*NK + k], gW[k*NEMB + e], acc);
        s_x[t] = X_emb[(i >> 4)*NEMB + e] + acc;
    }
    __syncthreads();
    // hx2 = ssp(x1 @ hW1 + hb1)
    if (t < NE*NK){
        const int i = t >> 3, k = t & 7;
        float acc = hb[NK + k];
#pragma unroll
        for (int e = 0; e < NEMB; e++)
            acc = fmaf(s_x[i*NEMB + e], hW[NEMB*NK + e*NK + k], acc);
        s_hx[t] = ssp(acc);
    }
    __syncthreads();
    // z2[i,k] = sum_j w2[i,j,k]*hx2[j,k] + sum_m wn2[i,m,k]*Y[m,k]
    if (t < NE*NK){
        const int i = t >> 3, k = t & 7;
        float z2 = 0.f;
#pragma unroll
        for (int j = 0; j < NE; j++)
            z2 = fmaf(bf2f(s_w2[i*W_STRIDE + j*NK + k]), s_hx[j*NK + k], z2);
#pragma unroll
        for (int m = 0; m < NA; m++)
            z2 = fmaf(bf2f(s_wn[1][i*WN_STRIDE + m*NK + k]), s_Y[m*NK + k], z2);
        s_z[t] = z2;
    }
    __syncthreads();
    // x2 = x1 + z2 @ gW1 + gb1
    if (t < NE*NEMB){
        const int i = t >> 4, e = t & 15;
        float acc = gb[NEMB + e];
#pragma unroll
        for (int k = 0; k < NK; k++)
            acc = fmaf(s_z[i*NK + k], gW[NK*NEMB + k*NEMB + e], acc);
        s_x[t] += acc;
    }
    __syncthreads();
    // readout: sum_i x2[i] @ orbW
    float part = (t < NE*NEMB) ? s_x[t] * orbW[t & 15] : 0.f;
#pragma unroll
    for (int off = 32; off > 0; off >>= 1) part += __shfl_down(part, off, 64);
    if (lane == 0) s_red[wid] = part;
    __syncthreads();
    if (t == 0){
        float r = 0.f;
#pragma unroll
        for (int w = 0; w < 16; w++) r += s_red[w];
        out[b] = r;
    }
}

extern "C" void kernel_launch(void* const* d_in, const int* in_sizes, int n_in,
                              void* d_out, int out_size, void* d_ws, size_t ws_size,
                              hipStream_t stream)
{
    const float* edges_elec = (const float*)d_in[0];
    const float* edges_nuc  = (const float*)d_in[1];
    const float* X_emb      = (const float*)d_in[2];
    const float* Yk         = (const float*)d_in[3];
    const float* wW1        = (const float*)d_in[4];
    const float* wb1        = (const float*)d_in[5];
    const float* wW2        = (const float*)d_in[6];
    const float* wb2        = (const float*)d_in[7];
    const float* hW         = (const float*)d_in[8];
    const float* hb         = (const float*)d_in[9];
    const float* gW         = (const float*)d_in[10];
    const float* gb         = (const float*)d_in[11];
    const float* orbW       = (const float*)d_in[12];

    jastrow_kernel<<<NB, 1024, 0, stream>>>(
        edges_elec, edges_nuc, X_emb, Yk, wW1, wb1, wW2, wb2, hW, hb,
        gW, gb, orbW, (float*)d_out);
}

// Round 10
// 143.484 us; speedup vs baseline: 1.0593x; 1.0282x over previous
//
#include <hip/hip_runtime.h>
#include <hip/hip_bf16.h>
#include <cstddef>
#include <cstdint>
#include <cstring>

// JastrowNet fully fused: ONE kernel, one block (1024 thr = 16 waves) per batch.
// Filter MLP (32->16->8, ssp) per 16-row tile:
//   MFMA-1: mfma_f32_16x16x32_bf16  D1 = W1^T x rows^T + b1
//   MFMA-2: mfma_f32_16x16x16_bf16  (K=16) -- B2 frag == D1 frag, no shuffles.
// R9 structure (shuffle-free filter phase, LDS filter buffers, scalar-loop
// contractions in the update phase) kept: best bench score (147.5).
// R10: (a) bf16 converts via __float2bfloat16 scalar casts (m240: compiler
// pattern-matches to native cvt; hand asm was -37%) replacing the 5-instr
// integer RNE sequence (~120 converts/wave); (b) z1/z2 update loops split
// into 4 independent accumulators (serial fmaf chain 40 -> 10 deep).
// Wave schedule: even wid -> same-spin, odd -> anti, 4 tiles each; all waves
// 1 nuclear tile.  Workspace unused.

#define NB   512
#define NE   32
#define NA   8
#define NF   32
#define NH   16
#define NK   8
#define NEMB 16

#define W_STRIDE  264   // shorts per i-row of s_w1/s_w2 (32*8 + 8 pad)
#define WN_STRIDE 72    // shorts per i-row of s_wn    ( 8*8 + 8 pad)

typedef __attribute__((ext_vector_type(8))) short short8;
typedef __attribute__((ext_vector_type(4))) short short4b;
typedef __attribute__((ext_vector_type(4))) float f32x4;

#define LN2 0.69314718055994530942f

// ssp(v) = softplus(v) - ln2; inputs bounded -> direct form safe.
__device__ __forceinline__ float ssp(float v){
    return __logf(1.f + __expf(v)) - LN2;
}

// fp32 -> bf16 via the HIP scalar cast (compiler emits the optimal native
// sequence on gfx950 -- m240: do NOT hand-write cvt_pk asm).
__device__ __forceinline__ short f2bf(float x){
    __hip_bfloat16 h = __float2bfloat16(x);
    unsigned short u;
    __builtin_memcpy(&u, &h, sizeof(u));
    return (short)u;
}
__device__ __forceinline__ unsigned packbf2(float lo, float hi){
    return (unsigned)(unsigned short)f2bf(lo) | ((unsigned)(unsigned short)f2bf(hi) << 16);
}
__device__ __forceinline__ float bf2f(short s){
    return __uint_as_float(((unsigned)(unsigned short)s) << 16);
}
__device__ __forceinline__ short8 cvt_row(float4 a, float4 b){
    short8 s;
    s[0]=f2bf(a.x); s[1]=f2bf(a.y); s[2]=f2bf(a.z); s[3]=f2bf(a.w);
    s[4]=f2bf(b.x); s[5]=f2bf(b.y); s[6]=f2bf(b.z); s[7]=f2bf(b.w);
    return s;
}

__device__ __forceinline__ f32x4 mfma16x16(short4b a, short4b b, f32x4 c){
#if __has_builtin(__builtin_amdgcn_mfma_f32_16x16x16bf16_1k)
    return __builtin_amdgcn_mfma_f32_16x16x16bf16_1k(a, b, c, 0, 0, 0);
#else
    f32x4 d;
    asm("s_nop 1\n\tv_mfma_f32_16x16x16_bf16 %0, %1, %2, %3\n\ts_nop 7"
        : "=v"(d) : "v"(a), "v"(b), "v"(c));
    return d;
#endif
}

extern "C" __global__ void __launch_bounds__(1024, 4)
jastrow_kernel(const float* __restrict__ edges_elec,
               const float* __restrict__ edges_nuc,
               const float* __restrict__ X_emb,
               const float* __restrict__ Yk,
               const float* __restrict__ wW1, const float* __restrict__ wb1,
               const float* __restrict__ wW2, const float* __restrict__ wb2,
               const float* __restrict__ hW,  const float* __restrict__ hb,
               const float* __restrict__ gW,  const float* __restrict__ gb,
               const float* __restrict__ orbW,
               float* __restrict__ out)
{
    __shared__ __align__(16) short s_w1[NE*W_STRIDE];        // 16896 B
    __shared__ __align__(16) short s_w2[NE*W_STRIDE];        // 16896 B
    __shared__ __align__(16) short s_wn[2][NE*WN_STRIDE];    //  9216 B
    __shared__ float s_hx1[2*NK];
    __shared__ float s_Y[NA*NK];                             //   256 B
    __shared__ float s_x[NE*NEMB];                           //  2048 B
    __shared__ float s_z[NE*NK];                             //  1024 B
    __shared__ float s_hx[NE*NK];                            //  1024 B
    __shared__ float s_red[16];
    // pre-converted weight fragments (transposed layouts)
    __shared__ __align__(16) short s_w1T[3][2][NH][NF];      //  6144 B
    __shared__ __align__(16) short s_w2T[3][2][16][NH];      //  3072 B
    __shared__ __align__(16) float s_b1[3][2][NH];
    __shared__ __align__(16) float s_b2[3][2][16];

    const int b = blockIdx.x, t = threadIdx.x;
    const int wid = t >> 6, lane = t & 63;
    const int r16 = lane & 15, g4 = lane >> 4;

    // ---- hoist this wave's edge loads (independent of LDS staging) ----
    const int ccE = wid & 1;
    const int wq  = (wid >> 1) * 4;
    auto esrc = [&](int u) -> const float* {
        const int tau = wq + u;
        const int qi = tau >> 4, g = tau & 15;
        const int qj = ccE ? (1 - qi) : qi;
        return edges_elec + (((size_t)b*NE + qi*16 + g)*NE + qj*16 + r16)*NF + g4*8;
    };
    float4 ra = ((const float4*)esrc(0))[0];
    float4 rb = ((const float4*)esrc(0))[1];
    const int nm = lane & 7;
    const int ni = 2*wid + (r16 >> 3);
    const float* nsrc = edges_nuc + (((size_t)b*NE + ni)*NA + nm)*NF + g4*8;
    const float4 nra = ((const float4*)nsrc)[0];
    const float4 nrb = ((const float4*)nsrc)[1];

    // ---- stage weight fragments (once per block, pre-converted bf16) ----
    for (int idx = t; idx < 3*2*NH*NF; idx += 1024){
        const int f = idx & 31, h = (idx >> 5) & 15;
        const int l = (idx >> 9) & 1, cc = idx >> 10;
        s_w1T[cc][l][h][f] = f2bf(wW1[((size_t)(l*3 + cc)*NF + f)*NH + h]);
    }
    for (int idx = t; idx < 3*2*16*NH; idx += 1024){
        const int h = idx & 15, k = (idx >> 4) & 15;
        const int l = (idx >> 8) & 1, cc = idx >> 9;
        s_w2T[cc][l][k][h] = (k < NK)
            ? f2bf(wW2[((size_t)(l*3 + cc)*NH + h)*NK + k]) : (short)0;
    }
    if (t < 3*2*NH){
        const int m = t & 15, l = (t >> 4) & 1, cc = t >> 5;
        s_b1[cc][l][m] = wb1[(l*3 + cc)*NH + m];
        s_b2[cc][l][m] = (m < NK) ? wb2[(l*3 + cc)*NK + m] : 0.f;
    }
    if (t >= 896 && t < 896 + NA*NK)
        s_Y[t - 896] = Yk[t - 896];
    // hx1[s][k] = ssp(X_emb[s] @ hW[0] + hb[0]) (spin-only)
    if (t >= 1008){
        const int tt = t - 1008;
        const int s = tt >> 3, k = tt & 7;
        float acc = hb[k];
#pragma unroll
        for (int e = 0; e < NEMB; e++)
            acc = fmaf(X_emb[s*NEMB + e], hW[e*NK + k], acc);
        s_hx1[tt] = ssp(acc);
    }
    __syncthreads();

    // ---- per-wave fragment fetch: electron channel ----
    short8 a1[2]; short4b a2[2]; f32x4 c1[2], c2[2];
#pragma unroll
    for (int l = 0; l < 2; l++){
        a1[l] = *(const short8*)&s_w1T[ccE][l][r16][g4*8];
        a2[l] = *(const short4b*)&s_w2T[ccE][l][r16][g4*4];
        c1[l] = *(const f32x4*)&s_b1[ccE][l][g4*4];
        c2[l] = *(const f32x4*)&s_b2[ccE][l][g4*4];
    }

#pragma unroll
    for (int u = 0; u < 4; u++){
        float4 nxa = ra, nxb = rb;           // defined at u==3 (self; dead after)
        if (u < 3){
            const float* src = esrc(u + 1);
            nxa = ((const float4*)src)[0];
            nxb = ((const float4*)src)[1];
        }
        const int tau = wq + u;
        const int qi = tau >> 4, g = tau & 15;
        const int qj = ccE ? (1 - qi) : qi;
        const int i  = qi*16 + g;
        const int j  = qj*16 + r16;
        const short8 bfr = cvt_row(ra, rb);
#pragma unroll
        for (int l = 0; l < 2; l++){
            f32x4 d1 = __builtin_amdgcn_mfma_f32_16x16x32_bf16(a1[l], bfr, c1[l], 0, 0, 0);
            short4b bb;
            bb[0] = f2bf(ssp(d1[0]));
            bb[1] = f2bf(ssp(d1[1]));
            bb[2] = f2bf(ssp(d1[2]));
            bb[3] = f2bf(ssp(d1[3]));
            f32x4 d2 = mfma16x16(a2[l], bb, c2[l]);
            float wk[4];
#pragma unroll
            for (int r = 0; r < 4; r++) wk[r] = ssp(d2[r]);
            if (ccE == 0 && r16 == g){
#pragma unroll
                for (int r = 0; r < 4; r++) wk[r] = 0.f;
            }
            if (g4 < 2){
                short* dst = l ? s_w2 : s_w1;
                uint2 uu;
                uu.x = packbf2(wk[0], wk[1]);
                uu.y = packbf2(wk[2], wk[3]);
                *(uint2*)&dst[i*W_STRIDE + j*NK + g4*4] = uu;
            }
        }
        ra = nxa; rb = nxb;
    }

    // ---- nuclear channel (all 16 waves, one tile each; loads hoisted) ----
    {
#pragma unroll
        for (int l = 0; l < 2; l++){
            a1[l] = *(const short8*)&s_w1T[2][l][r16][g4*8];
            a2[l] = *(const short4b*)&s_w2T[2][l][r16][g4*4];
            c1[l] = *(const f32x4*)&s_b1[2][l][g4*4];
            c2[l] = *(const f32x4*)&s_b2[2][l][g4*4];
        }
        const short8 bfr = cvt_row(nra, nrb);
#pragma unroll
        for (int l = 0; l < 2; l++){
            f32x4 d1 = __builtin_amdgcn_mfma_f32_16x16x32_bf16(a1[l], bfr, c1[l], 0, 0, 0);
            short4b bb;
            bb[0] = f2bf(ssp(d1[0]));
            bb[1] = f2bf(ssp(d1[1]));
            bb[2] = f2bf(ssp(d1[2]));
            bb[3] = f2bf(ssp(d1[3]));
            f32x4 d2 = mfma16x16(a2[l], bb, c2[l]);
            if (g4 < 2){
                uint2 uu;
                uu.x = packbf2(ssp(d2[0]), ssp(d2[1]));
                uu.y = packbf2(ssp(d2[2]), ssp(d2[3]));
                *(uint2*)&s_wn[l][ni*WN_STRIDE + nm*NK + g4*4] = uu;
            }
        }
    }
    __syncthreads();

    // ================= per-batch sequential update =================
    // z1[i,k] = sum_j w1[i,j,k]*hx1[spin(j),k] + sum_m wn1[i,m,k]*Y[m,k]
    if (t < NE*NK){
        const int i = t >> 3, k = t & 7;
        float p0a = 0.f, p0b = 0.f, p1a = 0.f, p1b = 0.f;   // ILP-4
#pragma unroll
        for (int j = 0; j < 16; j += 2){
            p0a += bf2f(s_w1[i*W_STRIDE + j*NK + k]);
            p0b += bf2f(s_w1[i*W_STRIDE + (j + 1)*NK + k]);
            p1a += bf2f(s_w1[i*W_STRIDE + (16 + j)*NK + k]);
            p1b += bf2f(s_w1[i*W_STRIDE + (17 + j)*NK + k]);
        }
        float z1 = (p0a + p0b)*s_hx1[k] + (p1a + p1b)*s_hx1[NK + k];
        float za = 0.f, zb = 0.f;
#pragma unroll
        for (int m = 0; m < NA; m += 2){
            za = fmaf(bf2f(s_wn[0][i*WN_STRIDE + m*NK + k]),       s_Y[m*NK + k],       za);
            zb = fmaf(bf2f(s_wn[0][i*WN_STRIDE + (m + 1)*NK + k]), s_Y[(m + 1)*NK + k], zb);
        }
        s_z[t] = z1 + za + zb;
    }
    __syncthreads();
    // x1 = x0 + z1 @ gW0 + gb0
    if (t < NE*NEMB){
        const int i = t >> 4, e = t & 15;
        float acc = gb[e];
#pragma unroll
        for (int k = 0; k < NK; k++)
            acc = fmaf(s_z[i*NK + k], gW[k*NEMB + e], acc);
        s_x[t] = X_emb[(i >> 4)*NEMB + e] + acc;
    }
    __syncthreads();
    // hx2 = ssp(x1 @ hW1 + hb1)
    if (t < NE*NK){
        const int i = t >> 3, k = t & 7;
        float acc = hb[NK + k];
#pragma unroll
        for (int e = 0; e < NEMB; e++)
            acc = fmaf(s_x[i*NEMB + e], hW[NEMB*NK + e*NK + k], acc);
        s_hx[t] = ssp(acc);
    }
    __syncthreads();
    // z2[i,k] = sum_j w2[i,j,k]*hx2[j,k] + sum_m wn2[i,m,k]*Y[m,k]
    if (t < NE*NK){
        const int i = t >> 3, k = t & 7;
        float za = 0.f, zb = 0.f, zc = 0.f, zd = 0.f;       // ILP-4
#pragma unroll
        for (int j = 0; j < NE; j += 4){
            za = fmaf(bf2f(s_w2[i*W_STRIDE + j*NK + k]),       s_hx[j*NK + k],       za);
            zb = fmaf(bf2f(s_w2[i*W_STRIDE + (j + 1)*NK + k]), s_hx[(j + 1)*NK + k], zb);
            zc = fmaf(bf2f(s_w2[i*W_STRIDE + (j + 2)*NK + k]), s_hx[(j + 2)*NK + k], zc);
            zd = fmaf(bf2f(s_w2[i*W_STRIDE + (j + 3)*NK + k]), s_hx[(j + 3)*NK + k], zd);
        }
#pragma unroll
        for (int m = 0; m < NA; m += 2){
            za = fmaf(bf2f(s_wn[1][i*WN_STRIDE + m*NK + k]),       s_Y[m*NK + k],       za);
            zb = fmaf(bf2f(s_wn[1][i*WN_STRIDE + (m + 1)*NK + k]), s_Y[(m + 1)*NK + k], zb);
        }
        s_z[t] = (za + zb) + (zc + zd);
    }
    __syncthreads();
    // x2 = x1 + z2 @ gW1 + gb1
    if (t < NE*NEMB){
        const int i = t >> 4, e = t & 15;
        float acc = gb[NEMB + e];
#pragma unroll
        for (int k = 0; k < NK; k++)
            acc = fmaf(s_z[i*NK + k], gW[NK*NEMB + k*NEMB + e], acc);
        s_x[t] += acc;
    }
    __syncthreads();
    // readout: sum_i x2[i] @ orbW
    float part = (t < NE*NEMB) ? s_x[t] * orbW[t & 15] : 0.f;
#pragma unroll
    for (int off = 32; off > 0; off >>= 1) part += __shfl_down(part, off, 64);
    if (lane == 0) s_red[wid] = part;
    __syncthreads();
    if (t == 0){
        float r = 0.f;
#pragma unroll
        for (int w = 0; w < 16; w++) r += s_red[w];
        out[b] = r;
    }
}

extern "C" void kernel_launch(void* const* d_in, const int* in_sizes, int n_in,
                              void* d_out, int out_size, void* d_ws, size_t ws_size,
                              hipStream_t stream)
{
    const float* edges_elec = (const float*)d_in[0];
    const float* edges_nuc  = (const float*)d_in[1];
    const float* X_emb      = (const float*)d_in[2];
    const float* Yk         = (const float*)d_in[3];
    const float* wW1        = (const float*)d_in[4];
    const float* wb1        = (const float*)d_in[5];
    const float* wW2        = (const float*)d_in[6];
    const float* wb2        = (const float*)d_in[7];
    const float* hW         = (const float*)d_in[8];
    const float* hb         = (const float*)d_in[9];
    const float* gW         = (const float*)d_in[10];
    const float* gb         = (const float*)d_in[11];
    const float* orbW       = (const float*)d_in[12];

    jastrow_kernel<<<NB, 1024, 0, stream>>>(
        edges_elec, edges_nuc, X_emb, Yk, wW1, wb1, wW2, wb2, hW, hb,
        gW, gb, orbW, (float*)d_out);
}

// Round 13
// 139.965 us; speedup vs baseline: 1.0859x; 1.0251x over previous
//
#include <hip/hip_runtime.h>
#include <hip/hip_bf16.h>
#include <cstddef>
#include <cstdint>
#include <cstring>

// JastrowNet fully fused: ONE kernel, one block (1024 thr = 16 waves) per batch.
// Filter MLP (32->16->8, ssp) per 16-row tile:
//   MFMA-1: mfma_f32_16x16x32_bf16  D1 = W1^T x rows^T + b1   (x2 layers)
//   MFMA-2: mfma_f32_16x16x16_bf16  (K=16) -- B2 frag == D1 frag, no shuffles.
// R11/R12 post-mortem: v_permlane32_swap_b32 semantics could not be pinned
// (both assumed directions failed) -> ABANDONED. R13 does the same d2-merge
// with the session-verified primitive __shfl_up:
//   merged[r] = (lane<32) ? d2_l0[r] : __shfl_up(d2_l1[r], 32)
// lanes 0-31 = layer-1 rows 0-7, lanes 32-63 = layer-2 rows 0-7 (lane 32+s
// reads lane s: same r16 -> same col; row (g4-2)*4+r -> k-offset (g4&1)*4).
// d2 ssp halves (8->4/tile); store becomes one uniform all-lanes write.
// Bias fold kept: b2' = b2 - ln2*sum_h W2bf[h,k] (exact algebra vs the bf16
// weights the MFMA uses), so d1 activation is plain softplus (ssp_nl).
// Rest identical to R10 (last pass: bench 143.5, kernel 45.4).  Workspace unused.

#define NB   512
#define NE   32
#define NA   8
#define NF   32
#define NH   16
#define NK   8
#define NEMB 16

#define W_STRIDE  264   // shorts per i-row of s_w1/s_w2 (32*8 + 8 pad)
#define WN_STRIDE 72    // shorts per i-row of s_wn    ( 8*8 + 8 pad)

typedef __attribute__((ext_vector_type(8))) short short8;
typedef __attribute__((ext_vector_type(4))) short short4b;
typedef __attribute__((ext_vector_type(4))) float f32x4;

#define LN2 0.69314718055994530942f

// full shifted-softplus (filter outputs)
__device__ __forceinline__ float ssp(float v){
    return __logf(1.f + __expf(v)) - LN2;
}
// softplus WITHOUT -ln2 (hidden layer; -ln2 folded into the c2 bias)
__device__ __forceinline__ float ssp_nl(float v){
    return __logf(1.f + __expf(v));
}

// fp32 -> bf16 via the HIP scalar cast (compiler emits native cvt; m240)
__device__ __forceinline__ short f2bf(float x){
    __hip_bfloat16 h = __float2bfloat16(x);
    unsigned short u;
    __builtin_memcpy(&u, &h, sizeof(u));
    return (short)u;
}
__device__ __forceinline__ unsigned packbf2(float lo, float hi){
    return (unsigned)(unsigned short)f2bf(lo) | ((unsigned)(unsigned short)f2bf(hi) << 16);
}
__device__ __forceinline__ float bf2f(short s){
    return __uint_as_float(((unsigned)(unsigned short)s) << 16);
}
__device__ __forceinline__ short8 cvt_row(float4 a, float4 b){
    short8 s;
    s[0]=f2bf(a.x); s[1]=f2bf(a.y); s[2]=f2bf(a.z); s[3]=f2bf(a.w);
    s[4]=f2bf(b.x); s[5]=f2bf(b.y); s[6]=f2bf(b.z); s[7]=f2bf(b.w);
    return s;
}

__device__ __forceinline__ f32x4 mfma16x16(short4b a, short4b b, f32x4 c){
#if __has_builtin(__builtin_amdgcn_mfma_f32_16x16x16bf16_1k)
    return __builtin_amdgcn_mfma_f32_16x16x16bf16_1k(a, b, c, 0, 0, 0);
#else
    f32x4 d;
    asm("s_nop 1\n\tv_mfma_f32_16x16x16_bf16 %0, %1, %2, %3\n\ts_nop 7"
        : "=v"(d) : "v"(a), "v"(b), "v"(c));
    return d;
#endif
}

extern "C" __global__ void __launch_bounds__(1024, 4)
jastrow_kernel(const float* __restrict__ edges_elec,
               const float* __restrict__ edges_nuc,
               const float* __restrict__ X_emb,
               const float* __restrict__ Yk,
               const float* __restrict__ wW1, const float* __restrict__ wb1,
               const float* __restrict__ wW2, const float* __restrict__ wb2,
               const float* __restrict__ hW,  const float* __restrict__ hb,
               const float* __restrict__ gW,  const float* __restrict__ gb,
               const float* __restrict__ orbW,
               float* __restrict__ out)
{
    __shared__ __align__(16) short s_w1[NE*W_STRIDE];        // 16896 B
    __shared__ __align__(16) short s_w2[NE*W_STRIDE];        // 16896 B
    __shared__ __align__(16) short s_wn[2][NE*WN_STRIDE];    //  9216 B
    __shared__ float s_hx1[2*NK];
    __shared__ float s_Y[NA*NK];                             //   256 B
    __shared__ float s_x[NE*NEMB];                           //  2048 B
    __shared__ float s_z[NE*NK];                             //  1024 B
    __shared__ float s_hx[NE*NK];                            //  1024 B
    __shared__ float s_red[16];
    // pre-converted weight fragments (transposed layouts)
    __shared__ __align__(16) short s_w1T[3][2][NH][NF];      //  6144 B
    __shared__ __align__(16) short s_w2T[3][2][16][NH];      //  3072 B
    __shared__ __align__(16) float s_b1[3][2][NH];
    __shared__ __align__(16) float s_b2[3][2][16];

    const int b = blockIdx.x, t = threadIdx.x;
    const int wid = t >> 6, lane = t & 63;
    const int r16 = lane & 15, g4 = lane >> 4;

    // ---- hoist this wave's edge loads (independent of LDS staging) ----
    const int ccE = wid & 1;
    const int wq  = (wid >> 1) * 4;
    auto esrc = [&](int u) -> const float* {
        const int tau = wq + u;
        const int qi = tau >> 4, g = tau & 15;
        const int qj = ccE ? (1 - qi) : qi;
        return edges_elec + (((size_t)b*NE + qi*16 + g)*NE + qj*16 + r16)*NF + g4*8;
    };
    float4 ra = ((const float4*)esrc(0))[0];
    float4 rb = ((const float4*)esrc(0))[1];
    const int nm = lane & 7;
    const int ni = 2*wid + (r16 >> 3);
    const float* nsrc = edges_nuc + (((size_t)b*NE + ni)*NA + nm)*NF + g4*8;
    const float4 nra = ((const float4*)nsrc)[0];
    const float4 nrb = ((const float4*)nsrc)[1];

    // ---- stage weight fragments (once per block, pre-converted bf16) ----
    for (int idx = t; idx < 3*2*NH*NF; idx += 1024){
        const int f = idx & 31, h = (idx >> 5) & 15;
        const int l = (idx >> 9) & 1, cc = idx >> 10;
        s_w1T[cc][l][h][f] = f2bf(wW1[((size_t)(l*3 + cc)*NF + f)*NH + h]);
    }
    for (int idx = t; idx < 3*2*16*NH; idx += 1024){
        const int h = idx & 15, k = (idx >> 4) & 15;
        const int l = (idx >> 8) & 1, cc = idx >> 9;
        s_w2T[cc][l][k][h] = (k < NK)
            ? f2bf(wW2[((size_t)(l*3 + cc)*NH + h)*NK + k]) : (short)0;
    }
    if (t < 3*2*NH){
        const int m = t & 15, l = (t >> 4) & 1, cc = t >> 5;
        s_b1[cc][l][m] = wb1[(l*3 + cc)*NH + m];
        float v = 0.f;
        if (m < NK){
            // fold -ln2 of the hidden ssp: b2' = b2 - ln2 * sum_h W2bf[h][m]
            v = wb2[(l*3 + cc)*NK + m];
            float s = 0.f;
#pragma unroll
            for (int h = 0; h < NH; h++)
                s += bf2f(f2bf(wW2[((size_t)(l*3 + cc)*NH + h)*NK + m]));
            v = fmaf(-LN2, s, v);
        }
        s_b2[cc][l][m] = v;
    }
    if (t >= 896 && t < 896 + NA*NK)
        s_Y[t - 896] = Yk[t - 896];
    // hx1[s][k] = ssp(X_emb[s] @ hW[0] + hb[0]) (spin-only)
    if (t >= 1008){
        const int tt = t - 1008;
        const int s = tt >> 3, k = tt & 7;
        float acc = hb[k];
#pragma unroll
        for (int e = 0; e < NEMB; e++)
            acc = fmaf(X_emb[s*NEMB + e], hW[e*NK + k], acc);
        s_hx1[tt] = ssp(acc);
    }
    __syncthreads();

    // ---- per-wave fragment fetch: electron channel ----
    short8 a1[2]; short4b a2[2]; f32x4 c1[2], c2[2];
#pragma unroll
    for (int l = 0; l < 2; l++){
        a1[l] = *(const short8*)&s_w1T[ccE][l][r16][g4*8];
        a2[l] = *(const short4b*)&s_w2T[ccE][l][r16][g4*4];
        c1[l] = *(const f32x4*)&s_b1[ccE][l][g4*4];
        c2[l] = *(const f32x4*)&s_b2[ccE][l][g4*4];
    }

#pragma unroll
    for (int u = 0; u < 4; u++){
        float4 nxa = ra, nxb = rb;           // defined at u==3 (self; dead after)
        if (u < 3){
            const float* src = esrc(u + 1);
            nxa = ((const float4*)src)[0];
            nxb = ((const float4*)src)[1];
        }
        const int tau = wq + u;
        const int qi = tau >> 4, g = tau & 15;
        const int qj = ccE ? (1 - qi) : qi;
        const int i  = qi*16 + g;
        const int j  = qj*16 + r16;
        const short8 bfr = cvt_row(ra, rb);

        f32x4 d1_0 = __builtin_amdgcn_mfma_f32_16x16x32_bf16(a1[0], bfr, c1[0], 0, 0, 0);
        f32x4 d1_1 = __builtin_amdgcn_mfma_f32_16x16x32_bf16(a1[1], bfr, c1[1], 0, 0, 0);
        short4b bb0, bb1;
#pragma unroll
        for (int r = 0; r < 4; r++){
            bb0[r] = f2bf(ssp_nl(d1_0[r]));
            bb1[r] = f2bf(ssp_nl(d1_1[r]));
        }
        f32x4 d2_0 = mfma16x16(a2[0], bb0, c2[0]);
        f32x4 d2_1 = mfma16x16(a2[1], bb1, c2[1]);

        // merge via shfl_up: lanes 0-31 = layer-1 rows 0-7 (d2_0),
        // lanes 32-63 = layer-2 rows 0-7 (d2_1 from lane-32).
        float wk[4];
#pragma unroll
        for (int r = 0; r < 4; r++){
            const float hi = __shfl_up(d2_1[r], 32);
            wk[r] = ssp((lane < 32) ? d2_0[r] : hi);
        }
        if (ccE == 0 && r16 == g){
#pragma unroll
            for (int r = 0; r < 4; r++) wk[r] = 0.f;
        }
        short* dst = (g4 < 2) ? s_w1 : s_w2;
        uint2 uu;
        uu.x = packbf2(wk[0], wk[1]);
        uu.y = packbf2(wk[2], wk[3]);
        *(uint2*)&dst[i*W_STRIDE + j*NK + (g4 & 1)*4] = uu;

        ra = nxa; rb = nxb;
    }

    // ---- nuclear channel (all 16 waves, one tile each; loads hoisted) ----
    {
#pragma unroll
        for (int l = 0; l < 2; l++){
            a1[l] = *(const short8*)&s_w1T[2][l][r16][g4*8];
            a2[l] = *(const short4b*)&s_w2T[2][l][r16][g4*4];
            c1[l] = *(const f32x4*)&s_b1[2][l][g4*4];
            c2[l] = *(const f32x4*)&s_b2[2][l][g4*4];
        }
        const short8 bfr = cvt_row(nra, nrb);
        f32x4 d1_0 = __builtin_amdgcn_mfma_f32_16x16x32_bf16(a1[0], bfr, c1[0], 0, 0, 0);
        f32x4 d1_1 = __builtin_amdgcn_mfma_f32_16x16x32_bf16(a1[1], bfr, c1[1], 0, 0, 0);
        short4b bb0, bb1;
#pragma unroll
        for (int r = 0; r < 4; r++){
            bb0[r] = f2bf(ssp_nl(d1_0[r]));
            bb1[r] = f2bf(ssp_nl(d1_1[r]));
        }
        f32x4 d2_0 = mfma16x16(a2[0], bb0, c2[0]);
        f32x4 d2_1 = mfma16x16(a2[1], bb1, c2[1]);
        float wk[4];
#pragma unroll
        for (int r = 0; r < 4; r++){
            const float hi = __shfl_up(d2_1[r], 32);
            wk[r] = ssp((lane < 32) ? d2_0[r] : hi);
        }
        short* dst = (g4 < 2) ? s_wn[0] : s_wn[1];
        uint2 uu;
        uu.x = packbf2(wk[0], wk[1]);
        uu.y = packbf2(wk[2], wk[3]);
        *(uint2*)&dst[ni*WN_STRIDE + nm*NK + (g4 & 1)*4] = uu;
    }
    __syncthreads();

    // ================= per-batch sequential update =================
    // z1[i,k] = sum_j w1[i,j,k]*hx1[spin(j),k] + sum_m wn1[i,m,k]*Y[m,k]
    if (t < NE*NK){
        const int i = t >> 3, k = t & 7;
        float p0a = 0.f, p0b = 0.f, p1a = 0.f, p1b = 0.f;   // ILP-4
#pragma unroll
        for (int j = 0; j < 16; j += 2){
            p0a += bf2f(s_w1[i*W_STRIDE + j*NK + k]);
            p0b += bf2f(s_w1[i*W_STRIDE + (j + 1)*NK + k]);
            p1a += bf2f(s_w1[i*W_STRIDE + (16 + j)*NK + k]);
            p1b += bf2f(s_w1[i*W_STRIDE + (17 + j)*NK + k]);
        }
        float z1 = (p0a + p0b)*s_hx1[k] + (p1a + p1b)*s_hx1[NK + k];
        float za = 0.f, zb = 0.f;
#pragma unroll
        for (int m = 0; m < NA; m += 2){
            za = fmaf(bf2f(s_wn[0][i*WN_STRIDE + m*NK + k]),       s_Y[m*NK + k],       za);
            zb = fmaf(bf2f(s_wn[0][i*WN_STRIDE + (m + 1)*NK + k]), s_Y[(m + 1)*NK + k], zb);
        }
        s_z[t] = z1 + za + zb;
    }
    __syncthreads();
    // x1 = x0 + z1 @ gW0 + gb0
    if (t < NE*NEMB){
        const int i = t >> 4, e = t & 15;
        float acc = gb[e];
#pragma unroll
        for (int k = 0; k < NK; k++)
            acc = fmaf(s_z[i*NK + k], gW[k*NEMB + e], acc);
        s_x[t] = X_emb[(i >> 4)*NEMB + e] + acc;
    }
    __syncthreads();
    // hx2 = ssp(x1 @ hW1 + hb1)
    if (t < NE*NK){
        const int i = t >> 3, k = t & 7;
        float acc = hb[NK + k];
#pragma unroll
        for (int e = 0; e < NEMB; e++)
            acc = fmaf(s_x[i*NEMB + e], hW[NEMB*NK + e*NK + k], acc);
        s_hx[t] = ssp(acc);
    }
    __syncthreads();
    // z2[i,k] = sum_j w2[i,j,k]*hx2[j,k] + sum_m wn2[i,m,k]*Y[m,k]
    if (t < NE*NK){
        const int i = t >> 3, k = t & 7;
        float za = 0.f, zb = 0.f, zc = 0.f, zd = 0.f;       // ILP-4
#pragma unroll
        for (int j = 0; j < NE; j += 4){
            za = fmaf(bf2f(s_w2[i*W_STRIDE + j*NK + k]),       s_hx[j*NK + k],       za);
            zb = fmaf(bf2f(s_w2[i*W_STRIDE + (j + 1)*NK + k]), s_hx[(j + 1)*NK + k], zb);
            zc = fmaf(bf2f(s_w2[i*W_STRIDE + (j + 2)*NK + k]), s_hx[(j + 2)*NK + k], zc);
            zd = fmaf(bf2f(s_w2[i*W_STRIDE + (j + 3)*NK + k]), s_hx[(j + 3)*NK + k], zd);
        }
#pragma unroll
        for (int m = 0; m < NA; m += 2){
            za = fmaf(bf2f(s_wn[1][i*WN_STRIDE + m*NK + k]),       s_Y[m*NK + k],       za);
            zb = fmaf(bf2f(s_wn[1][i*WN_STRIDE + (m + 1)*NK + k]), s_Y[(m + 1)*NK + k], zb);
        }
        s_z[t] = (za + zb) + (zc + zd);
    }
    __syncthreads();
    // x2 = x1 + z2 @ gW1 + gb1
    if (t < NE*NEMB){
        const int i = t >> 4, e = t & 15;
        float acc = gb[NEMB + e];
#pragma unroll
        for (int k = 0; k < NK; k++)
            acc = fmaf(s_z[i*NK + k], gW[NK*NEMB + k*NEMB + e], acc);
        s_x[t] += acc;
    }
    __syncthreads();
    // readout: sum_i x2[i] @ orbW
    float part = (t < NE*NEMB) ? s_x[t] * orbW[t & 15] : 0.f;
#pragma unroll
    for (int off = 32; off > 0; off >>= 1) part += __shfl_down(part, off, 64);
    if (lane == 0) s_red[wid] = part;
    __syncthreads();
    if (t == 0){
        float r = 0.f;
#pragma unroll
        for (int w = 0; w < 16; w++) r += s_red[w];
        out[b] = r;
    }
}

extern "C" void kernel_launch(void* const* d_in, const int* in_sizes, int n_in,
                              void* d_out, int out_size, void* d_ws, size_t ws_size,
                              hipStream_t stream)
{
    const float* edges_elec = (const float*)d_in[0];
    const float* edges_nuc  = (const float*)d_in[1];
    const float* X_emb      = (const float*)d_in[2];
    const float* Yk         = (const float*)d_in[3];
    const float* wW1        = (const float*)d_in[4];
    const float* wb1        = (const float*)d_in[5];
    const float* wW2        = (const float*)d_in[6];
    const float* wb2        = (const float*)d_in[7];
    const float* hW         = (const float*)d_in[8];
    const float* hb         = (const float*)d_in[9];
    const float* gW         = (const float*)d_in[10];
    const float* gb         = (const float*)d_in[11];
    const float* orbW       = (const float*)d_in[12];

    jastrow_kernel<<<NB, 1024, 0, stream>>>(
        edges_elec, edges_nuc, X_emb, Yk, wW1, wb1, wW2, wb2, hW, hb,
        gW, gb, orbW, (float*)d_out);
}